// Round 1
// baseline (376.299 us; speedup 1.0000x reference)
//
#include <hip/hip_runtime.h>

using u16 = unsigned short;
typedef __attribute__((ext_vector_type(8))) __bf16 bf16x8;
typedef __attribute__((ext_vector_type(4))) float f32x4;
typedef __attribute__((ext_vector_type(8))) u16 u16x8;

__device__ __forceinline__ u16 f2bf(float f) {
    union { float f; unsigned u; } x; x.f = f;
    unsigned r = x.u + 0x7fffu + ((x.u >> 16) & 1u);
    return (u16)(r >> 16);
}

constexpr int Hdim = 1024, Bdim = 2, Sdim = 2048, Dh = 64;
constexpr int NTOK = Bdim * Sdim; // 4096

// ---------------- cast x -> bf16 ----------------
__global__ void cast_x_kernel(const float* __restrict__ x, u16* __restrict__ xb, int n) {
    int i = blockIdx.x * blockDim.x + threadIdx.x;
    int stride = gridDim.x * blockDim.x;
    for (; i < n; i += stride) xb[i] = f2bf(x[i]);
}

// ---------------- cast + transpose 4 weights: T[n][k] = W[k][n] ----------------
__global__ void transpose_cast_w(const float* __restrict__ W0, const float* __restrict__ W1,
                                 const float* __restrict__ W2, const float* __restrict__ W3,
                                 u16* __restrict__ T0, u16* __restrict__ T1,
                                 u16* __restrict__ T2, u16* __restrict__ T3) {
    __shared__ float tile[32][33];
    const float* W; u16* T;
    switch (blockIdx.z) {
        case 0: W = W0; T = T0; break;
        case 1: W = W1; T = T1; break;
        case 2: W = W2; T = T2; break;
        default: W = W3; T = T3; break;
    }
    int bx = blockIdx.x * 32, by = blockIdx.y * 32;
    int tx = threadIdx.x, ty = threadIdx.y;
    #pragma unroll
    for (int i = 0; i < 4; ++i)
        tile[ty + i * 8][tx] = W[(size_t)(by + ty + i * 8) * Hdim + bx + tx];
    __syncthreads();
    #pragma unroll
    for (int i = 0; i < 4; ++i)
        T[(size_t)(bx + ty + i * 8) * Hdim + by + tx] = f2bf(tile[tx][ty + i * 8]);
}

// ---------------- bf16 GEMM: C[M][N] = A[M][K] * Bt[N][K]^T ----------------
// 128x128 tile, BK=32, 4 waves (2x2), each wave 64x64 (4x4 fragments of 16x16).
template <typename OutT>
__global__ __launch_bounds__(256) void gemm_bt(const u16* __restrict__ A, const u16* __restrict__ Bt,
                                               OutT* __restrict__ C, int M, int N, int K) {
    __shared__ __align__(16) u16 As[128][40];
    __shared__ __align__(16) u16 Bs[128][40];
    const int tid = threadIdx.x;
    const int lane = tid & 63, wid = tid >> 6;
    const int wr = wid >> 1, wc = wid & 1;
    const int fr = lane & 15, k8 = (lane >> 4) * 8;
    const int rowBase = blockIdx.y * 128, colBase = blockIdx.x * 128;
    f32x4 acc[4][4] = {};
    for (int k0 = 0; k0 < K; k0 += 32) {
        __syncthreads();
        #pragma unroll
        for (int i = 0; i < 2; ++i) {
            int c = tid + 256 * i;
            int r = c >> 2, cc = (c & 3) * 8;
            *reinterpret_cast<u16x8*>(&As[r][cc]) =
                *reinterpret_cast<const u16x8*>(&A[(size_t)(rowBase + r) * K + k0 + cc]);
            *reinterpret_cast<u16x8*>(&Bs[r][cc]) =
                *reinterpret_cast<const u16x8*>(&Bt[(size_t)(colBase + r) * K + k0 + cc]);
        }
        __syncthreads();
        bf16x8 af[4], bfr[4];
        #pragma unroll
        for (int m = 0; m < 4; ++m)
            af[m] = *reinterpret_cast<const bf16x8*>(&As[wr * 64 + m * 16 + fr][k8]);
        #pragma unroll
        for (int n = 0; n < 4; ++n)
            bfr[n] = *reinterpret_cast<const bf16x8*>(&Bs[wc * 64 + n * 16 + fr][k8]);
        #pragma unroll
        for (int m = 0; m < 4; ++m)
            #pragma unroll
            for (int n = 0; n < 4; ++n)
                acc[m][n] = __builtin_amdgcn_mfma_f32_16x16x32_bf16(af[m], bfr[n], acc[m][n], 0, 0, 0);
    }
    #pragma unroll
    for (int m = 0; m < 4; ++m) {
        #pragma unroll
        for (int n = 0; n < 4; ++n) {
            int row = rowBase + wr * 64 + m * 16 + (lane >> 4) * 4;
            int col = colBase + wc * 64 + n * 16 + fr;
            #pragma unroll
            for (int j = 0; j < 4; ++j) {
                float v = acc[m][n][j];
                if constexpr (sizeof(OutT) == 2) C[(size_t)(row + j) * N + col] = f2bf(v);
                else                             C[(size_t)(row + j) * N + col] = v;
            }
        }
    }
}

// ---------------- causal flash attention ----------------
// grid: (S/64, NH, B). 4 waves; wave w owns q rows [qb*64 + w*16, +16).
// KV tiles of 64. Q,K direct from global (bf16x8 frags). V staged transposed in LDS.
__global__ __launch_bounds__(256) void attn_kernel(const u16* __restrict__ Q, const u16* __restrict__ Km,
                                                   const u16* __restrict__ Vm, u16* __restrict__ AO) {
    __shared__ __align__(16) u16 Vt[64][72];
    __shared__ __align__(16) u16 Pw[4][16][72];
    const int tid = threadIdx.x, lane = tid & 63, w = tid >> 6;
    const int qb = blockIdx.x, h = blockIdx.y, b = blockIdx.z;
    const int h0 = h * Dh;
    const size_t boff = (size_t)b * Sdim * Hdim;
    const u16* Qb = Q + boff;
    const u16* Kb = Km + boff;
    const u16* Vb = Vm + boff;
    u16* AOb = AO + boff;
    const int qbase = qb * 64;
    const int qrow0 = qbase + w * 16;
    const int fr = lane & 15, g = lane >> 4, k8 = g * 8;

    bf16x8 qf[2];
    #pragma unroll
    for (int c = 0; c < 2; ++c)
        qf[c] = *reinterpret_cast<const bf16x8*>(&Qb[(size_t)(qrow0 + fr) * Hdim + h0 + c * 32 + k8]);

    f32x4 o[4] = {};
    float mrow[4], lrow[4];
    #pragma unroll
    for (int j = 0; j < 4; ++j) { mrow[j] = -INFINITY; lrow[j] = 0.f; }

    const int ntile = qb + 1;
    for (int t = 0; t < ntile; ++t) {
        const int kv0 = t * 64;
        __syncthreads();  // protect Vt from previous iteration's readers
        #pragma unroll
        for (int i = 0; i < 16; ++i) {
            int e = tid + 256 * i;
            int r = e >> 6, c = e & 63;
            Vt[c][r] = Vb[(size_t)(kv0 + r) * Hdim + h0 + c];
        }
        __syncthreads();

        // QK^T: s[n] = Q(16x64) . K^T(64x16), n-th 16-col kv tile
        f32x4 s[4];
        #pragma unroll
        for (int n = 0; n < 4; ++n) {
            const u16* kr = &Kb[(size_t)(kv0 + n * 16 + fr) * Hdim + h0];
            bf16x8 kf0 = *reinterpret_cast<const bf16x8*>(&kr[k8]);
            bf16x8 kf1 = *reinterpret_cast<const bf16x8*>(&kr[32 + k8]);
            f32x4 z = {};
            z    = __builtin_amdgcn_mfma_f32_16x16x32_bf16(qf[0], kf0, z, 0, 0, 0);
            s[n] = __builtin_amdgcn_mfma_f32_16x16x32_bf16(qf[1], kf1, z, 0, 0, 0);
        }

        // online softmax (row r held by lane group g, reg j -> r = g*4+j)
        #pragma unroll
        for (int j = 0; j < 4; ++j) {
            const int qrow = qrow0 + g * 4 + j;
            float mx = -INFINITY;
            #pragma unroll
            for (int n = 0; n < 4; ++n) {
                int kv = kv0 + n * 16 + fr;
                float v = s[n][j] * 0.125f;
                v = (kv <= qrow) ? v : -INFINITY;
                s[n][j] = v;
                mx = fmaxf(mx, v);
            }
            #pragma unroll
            for (int off = 1; off < 16; off <<= 1) mx = fmaxf(mx, __shfl_xor(mx, off));
            const float mnew = fmaxf(mrow[j], mx);
            const float alpha = __expf(mrow[j] - mnew);
            float rs = 0.f;
            #pragma unroll
            for (int n = 0; n < 4; ++n) {
                float p = __expf(s[n][j] - mnew);
                rs += p;
                Pw[w][g * 4 + j][n * 16 + fr] = f2bf(p);
            }
            #pragma unroll
            for (int off = 1; off < 16; off <<= 1) rs += __shfl_xor(rs, off);
            lrow[j] = lrow[j] * alpha + rs;
            mrow[j] = mnew;
            #pragma unroll
            for (int n = 0; n < 4; ++n) o[n][j] *= alpha;
        }

        // PV: O(16x64) += P(16x64) . V(64x64); P via per-wave LDS (same-wave RAW)
        bf16x8 pa0 = *reinterpret_cast<const bf16x8*>(&Pw[w][fr][k8]);
        bf16x8 pa1 = *reinterpret_cast<const bf16x8*>(&Pw[w][fr][32 + k8]);
        #pragma unroll
        for (int n = 0; n < 4; ++n) {
            bf16x8 vb0 = *reinterpret_cast<const bf16x8*>(&Vt[n * 16 + fr][k8]);
            bf16x8 vb1 = *reinterpret_cast<const bf16x8*>(&Vt[n * 16 + fr][32 + k8]);
            o[n] = __builtin_amdgcn_mfma_f32_16x16x32_bf16(pa0, vb0, o[n], 0, 0, 0);
            o[n] = __builtin_amdgcn_mfma_f32_16x16x32_bf16(pa1, vb1, o[n], 0, 0, 0);
        }
    }

    #pragma unroll
    for (int n = 0; n < 4; ++n) {
        #pragma unroll
        for (int j = 0; j < 4; ++j) {
            int qrow = qrow0 + g * 4 + j;
            AOb[(size_t)qrow * Hdim + h0 + n * 16 + fr] = f2bf(o[n][j] / lrow[j]);
        }
    }
}

extern "C" void kernel_launch(void* const* d_in, const int* in_sizes, int n_in,
                              void* d_out, int out_size, void* d_ws, size_t ws_size,
                              hipStream_t stream) {
    const float* x  = (const float*)d_in[0];
    // d_in[1] = mask (causal tril) — structure is known, applied analytically
    const float* Wq = (const float*)d_in[2];
    const float* Wk = (const float*)d_in[3];
    const float* Wv = (const float*)d_in[4];
    const float* Wo = (const float*)d_in[5];
    float* out = (float*)d_out;

    u16* ws  = (u16*)d_ws;
    u16* Xb  = ws;                    // 4096x1024
    u16* WqT = ws  + 4194304;         // 1024x1024 each, transposed [n][k]
    u16* WkT = WqT + 1048576;
    u16* WvT = WkT + 1048576;
    u16* WoT = WvT + 1048576;
    u16* Qm  = WoT + 1048576;         // 4096x1024 token-major
    u16* Km  = Qm  + 4194304;
    u16* Vm  = Km  + 4194304;
    u16* AO  = Vm  + 4194304;         // attention out, merged heads

    cast_x_kernel<<<2048, 256, 0, stream>>>(x, Xb, NTOK * Hdim);
    transpose_cast_w<<<dim3(32, 32, 4), dim3(32, 8), 0, stream>>>(Wq, Wk, Wv, Wo, WqT, WkT, WvT, WoT);
    gemm_bt<u16><<<dim3(8, 32), 256, 0, stream>>>(Xb, WqT, Qm, NTOK, Hdim, Hdim);
    gemm_bt<u16><<<dim3(8, 32), 256, 0, stream>>>(Xb, WkT, Km, NTOK, Hdim, Hdim);
    gemm_bt<u16><<<dim3(8, 32), 256, 0, stream>>>(Xb, WvT, Vm, NTOK, Hdim, Hdim);
    attn_kernel<<<dim3(Sdim / 64, 16, Bdim), 256, 0, stream>>>(Qm, Km, Vm, AO);
    gemm_bt<float><<<dim3(8, 32), 256, 0, stream>>>(AO, WoT, out, NTOK, Hdim, Hdim);
}